// Round 4
// baseline (747.763 us; speedup 1.0000x reference)
//
#include <hip/hip_runtime.h>
#include <hip/hip_bf16.h>

#define D_DIM 512
#define NSEQ  4096
#define BATCH 4
#define SCALE 0.125f

typedef __attribute__((ext_vector_type(8)))  short short8;
typedef __attribute__((ext_vector_type(16))) float floatx16;

__device__ __forceinline__ unsigned short f2bf(float f) {
    __hip_bfloat16 h = __float2bfloat16(f);
    return *reinterpret_cast<unsigned short*>(&h);
}

__device__ __forceinline__ floatx16 mfma_bf16(short8 a, short8 b, floatx16 c) {
    return __builtin_amdgcn_mfma_f32_32x32x16_bf16(a, b, c, 0, 0, 0);
}

// global -> LDS direct DMA, 16 B per lane. LDS dest must be wave-uniform base
// (HW adds lane*16). Global source is per-lane.
#define GLOAD16(g, l) __builtin_amdgcn_global_load_lds( \
    (const __attribute__((address_space(1))) unsigned int*)(g), \
    (__attribute__((address_space(3))) unsigned int*)(l), 16, 0, 0)

// ============================================================
// Kernel 0: cast x (4x4096x512) and W (1536x512) fp32 -> bf16.
// ============================================================
__global__ __launch_bounds__(256) void cast_inputs(
    const float* __restrict__ x, const float* __restrict__ W,
    unsigned short* __restrict__ xb, unsigned short* __restrict__ Wb)
{
    const size_t NX = (size_t)BATCH * NSEQ * D_DIM;      // 8388608
    size_t i = ((size_t)blockIdx.x * 256 + threadIdx.x) * 8;
    const float* src; unsigned short* dst;
    if (i < NX) { src = x + i; dst = xb + i; }
    else        { src = W + (i - NX); dst = Wb + (i - NX); }
    float4 v0 = *(const float4*)(src);
    float4 v1 = *(const float4*)(src + 4);
    short8 h;
    h[0] = (short)f2bf(v0.x); h[1] = (short)f2bf(v0.y);
    h[2] = (short)f2bf(v0.z); h[3] = (short)f2bf(v0.w);
    h[4] = (short)f2bf(v1.x); h[5] = (short)f2bf(v1.y);
    h[6] = (short)f2bf(v1.z); h[7] = (short)f2bf(v1.w);
    *(short8*)dst = h;
}

// ============================================================
// Kernel 1: QKV projection. BM=BN=128, BK=64, global_load_lds staging.
// Grid is e-major (dim3(12,128)): consecutive blocks share the A-panel in L2.
// V blocks (n0 >= 1024) transpose through LDS -> coalesced 16B vT stores.
// ============================================================
__global__ __launch_bounds__(256, 2) void qkv_gemm(
    const unsigned short* __restrict__ xb, const unsigned short* __restrict__ Wb,
    const float* __restrict__ bias,
    unsigned short* __restrict__ qs, unsigned short* __restrict__ kk,
    unsigned short* __restrict__ vT)
{
    __shared__ __align__(16) unsigned short S2[2][128 * 64];
    unsigned short* Xs = S2[0];
    unsigned short* Ws = S2[1];
    unsigned short* Tr = &S2[0][0];                    // [128 d][16 slots x 16B] for V

    const int t = threadIdx.x;
    const int lane = t & 63, w = t >> 6;
    const int l31 = lane & 31, lh = lane >> 5;
    const int wm = w >> 1, we = w & 1;
    const int n0 = blockIdx.x * 128;                   // e-dim (12 blocks)
    const int m0 = blockIdx.y * 128;                   // token-dim (128 blocks)

    floatx16 a00, a01, a10, a11;
#pragma unroll
    for (int r = 0; r < 16; r++) { a00[r] = 0.f; a01[r] = 0.f; a10[r] = 0.f; a11[r] = 0.f; }

    // per-thread staging coords: chunk p covers LDS bytes o = p*4096 + t*16
    int rowp[4], colp[4];
#pragma unroll
    for (int p = 0; p < 4; p++) {
        int o = p * 4096 + t * 16;
        int row = o >> 7;                          // 128 B per row
        int sl  = ((o >> 4) & 7) ^ (row & 7);      // global 16B-slot for this LDS slot
        rowp[p] = row; colp[p] = sl * 8;
    }

    for (int kc = 0; kc < 8; kc++) {
        const int k0 = kc * 64;
        __syncthreads();
#pragma unroll
        for (int p = 0; p < 4; p++) {
            GLOAD16(xb + (size_t)(m0 + rowp[p]) * D_DIM + k0 + colp[p],
                    (char*)Xs + p * 4096 + (t & ~63) * 16);
            GLOAD16(Wb + (size_t)(n0 + rowp[p]) * D_DIM + k0 + colp[p],
                    (char*)Ws + p * 4096 + (t & ~63) * 16);
        }
        __syncthreads();
        const int sw = l31 & 7;
#pragma unroll
        for (int ks = 0; ks < 4; ks++) {
            const int s = ks * 2 + lh;
            const int cof = ((s ^ sw) * 8);
            short8 fa0 = *(const short8*)&Xs[(wm * 64 +      l31) * 64 + cof];
            short8 fa1 = *(const short8*)&Xs[(wm * 64 + 32 + l31) * 64 + cof];
            short8 fb0 = *(const short8*)&Ws[(we * 64 +      l31) * 64 + cof];
            short8 fb1 = *(const short8*)&Ws[(we * 64 + 32 + l31) * 64 + cof];
            a00 = mfma_bf16(fa0, fb0, a00);
            a01 = mfma_bf16(fa0, fb1, a01);
            a10 = mfma_bf16(fa1, fb0, a10);
            a11 = mfma_bf16(fa1, fb1, a11);
        }
    }

    // epilogue: C/D layout col = lane&31, row = (r&3)+8*(r>>2)+4*lh
    if (n0 < 1024) {
        // q and k paths: direct scatter (2B stores, lane-consecutive e -> coalesced)
#pragma unroll
        for (int jt = 0; jt < 2; jt++) {
            const int e = n0 + we * 64 + jt * 32 + l31;
            const float bv = bias[e];
#pragma unroll
            for (int it = 0; it < 2; it++) {
                const int mb = m0 + wm * 64 + it * 32;
                const floatx16& av = (it == 0) ? ((jt == 0) ? a00 : a01)
                                               : ((jt == 0) ? a10 : a11);
                if (e < 512) {
#pragma unroll
                    for (int r = 0; r < 16; r++) {
                        int m = mb + (r & 3) + 8 * (r >> 2) + 4 * lh;
                        qs[(size_t)m * D_DIM + e] = f2bf((av[r] + bv) * SCALE);
                    }
                } else {
#pragma unroll
                    for (int r = 0; r < 16; r++) {
                        int m = mb + (r & 3) + 8 * (r >> 2) + 4 * lh;
                        kk[(size_t)m * D_DIM + (e - 512)] = f2bf(av[r] + bv);
                    }
                }
            }
        }
    } else {
        // V path: transpose through LDS (XOR-swizzled [128 d][16 slots of 16B]),
        // then coalesced 16B stores along tok into vT[b][d][tok].
        __syncthreads();                               // K-loop readers done
#pragma unroll
        for (int jt = 0; jt < 2; jt++) {
            const int dd = we * 64 + jt * 32 + l31;    // d within block tile
            const float bv = bias[n0 + dd];
#pragma unroll
            for (int it = 0; it < 2; it++) {
                const floatx16& av = (it == 0) ? ((jt == 0) ? a00 : a01)
                                               : ((jt == 0) ? a10 : a11);
#pragma unroll
                for (int q = 0; q < 4; q++) {
                    int tt = wm * 64 + it * 32 + 8 * q + 4 * lh;   // tok within tile
                    ushort4 hv;
                    hv.x = f2bf(av[4 * q + 0] + bv); hv.y = f2bf(av[4 * q + 1] + bv);
                    hv.z = f2bf(av[4 * q + 2] + bv); hv.w = f2bf(av[4 * q + 3] + bv);
                    int byte = dd * 256 + ((((tt >> 3) ^ (dd & 7)) << 4)) + ((tt & 7) << 1);
                    *(ushort4*)((char*)Tr + byte) = hv;
                }
            }
        }
        __syncthreads();
        // Read-out: 16 lanes sweep one d-row (16 chunks x 16B = 128 toks);
        // 8 row-groups cover all 128 d. Fully coalesced 16B global stores.
        const int rown = t >> 4;                       // 0..15
        const int c    = t & 15;                       // 16B chunk = 8 toks
        const int bb = m0 >> 12, tok0 = (m0 & 4095);
#pragma unroll
        for (int g = 0; g < 8; g++) {
            int row = g * 16 + rown;
            int byte = row * 256 + ((c ^ (row & 7)) << 4);
            uint4 v = *(const uint4*)((char*)Tr + byte);
            *(uint4*)(vT + ((size_t)bb * 512 + (n0 - 1024) + row) * 4096
                      + tok0 + c * 8) = v;
        }
    }
}

// ============================================================
// Kernel 2: flash attention, bf16 MFMA, async-split staging (T14) + setprio.
// 512 threads / 8 waves. BQ=64, BK=256. S computed transposed (K·Q^T).
// __launch_bounds__(512, 1): LDS (123 KB) caps us at 1 block/CU anyway;
// the ",2" variant halved the VGPR budget to 128 and spilled ~80 regs to
// LDS+scratch (R3: WRITE_SIZE 33MB->1.5GB, +16KB LDS). 256-VGPR budget
// keeps the 10 in-flight staging uint4s in registers.
// ============================================================
#define FA_BQ 64
#define FA_BK 256
#define FA_DC 128
#define QC_STR 136
#define KC_STR 136
#define P_STR  264
#define VT_STR 72

__global__ __launch_bounds__(512, 1) void flash_attn(
    const unsigned short* __restrict__ qs, const unsigned short* __restrict__ kk,
    const unsigned short* __restrict__ vT, float* __restrict__ out)
{
    __shared__ __align__(16) unsigned char smem[123392];
    unsigned short* Qc = (unsigned short*)(smem);            // [64][136]  (union w/ Vt)
    unsigned short* Kc = (unsigned short*)(smem + 17408);    // [256][136] (union w/ Vt)
    unsigned short* Vt = (unsigned short*)(smem);            // [512][72]
    unsigned short* P  = (unsigned short*)(smem + 87040);    // [64][264]
    float* pmax    = (float*)(smem + 120832);                // [64][4]
    float* psum    = (float*)(smem + 121856);                // [64][4]
    float* alpha_s = (float*)(smem + 122880);                // [64]
    float* l_s     = (float*)(smem + 123136);                // [64]

    const int t = threadIdx.x;
    const int lane = t & 63, w = t >> 6;
    const int l31 = lane & 31, lh = lane >> 5;
    const int wi = w & 1, wjj = w >> 1;
    const int b  = blockIdx.y;
    const int q0 = blockIdx.x * FA_BQ;
    const size_t qbase = ((size_t)b * NSEQ + q0) * D_DIM;
    const size_t kbase = (size_t)b * NSEQ * D_DIM;
    const size_t vbase = (size_t)b * D_DIM * NSEQ;           // vT[b][d][tok]

    const int i_my = wi * 32 + l31;                          // softmax row (0..63)

    // per-thread staging constants (row/col decomposition is p-invariant)
    const int gqk0 = (t >> 4) * D_DIM + (t & 15) * 8;        // Q/K global elem offset
    const int gv0  = (t >> 3) * NSEQ  + (t & 7) * 8;         // V  global elem offset
    const int lqk0 = (t >> 4) * QC_STR + (t & 15) * 8;       // QC_STR == KC_STR
    const int lv0  = (t >> 3) * VT_STR + (t & 7) * 8;

    uint4 rq[2], rk[8];                                       // in-flight staging regs

#define ISSUE_QK(kt_, dc_) do {                                               \
    _Pragma("unroll")                                                         \
    for (int p = 0; p < 2; p++)                                               \
        rq[p] = *(const uint4*)(qs + qbase + gqk0 + p * 32 * D_DIM + (dc_));  \
    _Pragma("unroll")                                                         \
    for (int p = 0; p < 8; p++)                                               \
        rk[p] = *(const uint4*)(kk + kbase + gqk0 + p * 32 * D_DIM            \
                                + (size_t)(kt_) * D_DIM + (dc_));             \
} while (0)

#define ISSUE_V(kt_, jc_) do {                                                \
    _Pragma("unroll")                                                         \
    for (int p = 0; p < 8; p++)                                               \
        rk[p] = *(const uint4*)(vT + vbase + gv0 + p * 64 * NSEQ              \
                                + (kt_) + (jc_) * 64);                        \
} while (0)

#define WRITE_QK() do {                                                       \
    _Pragma("unroll")                                                         \
    for (int p = 0; p < 2; p++) *(uint4*)&Qc[lqk0 + p * 32 * QC_STR] = rq[p]; \
    _Pragma("unroll")                                                         \
    for (int p = 0; p < 8; p++) *(uint4*)&Kc[lqk0 + p * 32 * KC_STR] = rk[p]; \
} while (0)

#define WRITE_V() do {                                                        \
    _Pragma("unroll")                                                         \
    for (int p = 0; p < 8; p++) *(uint4*)&Vt[lv0 + p * 64 * VT_STR] = rk[p];  \
} while (0)

    floatx16 o00, o01, o10, o11;                             // o[it][dtt]
#pragma unroll
    for (int r = 0; r < 16; r++) { o00[r] = 0.f; o01[r] = 0.f; o10[r] = 0.f; o11[r] = 0.f; }
    float m_st = -__builtin_inff(), l_st = 0.f;

    ISSUE_QK(0, 0);                                          // prologue prefetch

    for (int kt = 0; kt < NSEQ; kt += FA_BK) {
        // ---------------- S^T = K Q^T ----------------
        floatx16 s0, s1;
#pragma unroll
        for (int r = 0; r < 16; r++) { s0[r] = 0.f; s1[r] = 0.f; }

#pragma unroll
        for (int dc = 0; dc < D_DIM; dc += FA_DC) {
            __syncthreads();                                 // prev readers done
            WRITE_QK();                                      // publish prefetched tile
            __syncthreads();
            if (dc + FA_DC < D_DIM) ISSUE_QK(kt, dc + FA_DC);
            else                    ISSUE_V(kt, 0);          // covers softmax too
            const unsigned short* kr0 = &Kc[(wjj * 64 + l31) * KC_STR];
            const unsigned short* kr1 = kr0 + 32 * KC_STR;
            const unsigned short* qr  = &Qc[i_my * QC_STR];
            __builtin_amdgcn_s_setprio(1);
#pragma unroll
            for (int ks = 0; ks < 8; ks++) {
                const int co = ks * 16 + lh * 8;
                short8 fa0 = *(const short8*)(kr0 + co);
                short8 fa1 = *(const short8*)(kr1 + co);
                short8 fb  = *(const short8*)(qr + co);
                s0 = mfma_bf16(fa0, fb, s0);
                s1 = mfma_bf16(fa1, fb, s1);
            }
            __builtin_amdgcn_s_setprio(0);
        }

        // ---------------- online softmax (S^T: col=i on lane&31, rows=j) ----
        float mx = -__builtin_inff();
#pragma unroll
        for (int r = 0; r < 16; r++) mx = fmaxf(mx, fmaxf(s0[r], s1[r]));
        mx = fmaxf(mx, __shfl_xor(mx, 32));
        if (lh == 0) pmax[i_my * 4 + wjj] = mx;
        __syncthreads();
        float4 pm = *(float4*)&pmax[i_my * 4];
        const float m_new = fmaxf(m_st, fmaxf(fmaxf(pm.x, pm.y), fmaxf(pm.z, pm.w)));
        const float alpha = __expf(m_st - m_new);
        m_st = m_new;

        float sum = 0.f;
        {
            const int prow = i_my * P_STR;
#pragma unroll
            for (int q = 0; q < 4; q++) {
                float p0 = __expf(s0[4*q+0] - m_new), p1 = __expf(s0[4*q+1] - m_new);
                float p2 = __expf(s0[4*q+2] - m_new), p3 = __expf(s0[4*q+3] - m_new);
                sum += (p0 + p1) + (p2 + p3);
                ushort4 h; h.x = f2bf(p0); h.y = f2bf(p1); h.z = f2bf(p2); h.w = f2bf(p3);
                *(ushort4*)&P[prow + (wjj*2+0)*32 + 8*q + 4*lh] = h;
            }
#pragma unroll
            for (int q = 0; q < 4; q++) {
                float p0 = __expf(s1[4*q+0] - m_new), p1 = __expf(s1[4*q+1] - m_new);
                float p2 = __expf(s1[4*q+2] - m_new), p3 = __expf(s1[4*q+3] - m_new);
                sum += (p0 + p1) + (p2 + p3);
                ushort4 h; h.x = f2bf(p0); h.y = f2bf(p1); h.z = f2bf(p2); h.w = f2bf(p3);
                *(ushort4*)&P[prow + (wjj*2+1)*32 + 8*q + 4*lh] = h;
            }
        }
        sum += __shfl_xor(sum, 32);
        if (lh == 0) psum[i_my * 4 + wjj] = sum;
        if (lh == 0 && wjj == 0) alpha_s[i_my] = alpha;
        __syncthreads();
        float4 ps = *(float4*)&psum[i_my * 4];
        l_st = l_st * alpha + ((ps.x + ps.y) + (ps.z + ps.w));

        // ---------------- rescale O by alpha (skip if all == 1) -------------
        float av[2][16];
        bool ch = false;
#pragma unroll
        for (int it = 0; it < 2; it++)
#pragma unroll
            for (int q = 0; q < 4; q++) {
                float4 a4 = *(float4*)&alpha_s[it * 32 + 8 * q + 4 * lh];
                av[it][4*q+0] = a4.x; av[it][4*q+1] = a4.y;
                av[it][4*q+2] = a4.z; av[it][4*q+3] = a4.w;
                ch = ch || (a4.x != 1.f) || (a4.y != 1.f) || (a4.z != 1.f) || (a4.w != 1.f);
            }
        if (__any(ch)) {
#pragma unroll
            for (int r = 0; r < 16; r++) {
                o00[r] *= av[0][r]; o01[r] *= av[0][r];
                o10[r] *= av[1][r]; o11[r] *= av[1][r];
            }
        }

        // ---------------- O += P V  (wave w owns d-chunk w*64) --------------
#pragma unroll
        for (int jc = 0; jc < 4; jc++) {
            __syncthreads();                                 // prev readers done
            WRITE_V();                                       // publish prefetched V
            __syncthreads();
            if (jc < 3) ISSUE_V(kt, jc + 1);
            else        ISSUE_QK((kt + FA_BK < NSEQ) ? kt + FA_BK : kt, 0);
            const unsigned short* pr0 = &P[l31 * P_STR + jc * 64];
            const unsigned short* pr1 = &P[(32 + l31) * P_STR + jc * 64];
            const unsigned short* vr0 = &Vt[(w * 64 + l31) * VT_STR];
            const unsigned short* vr1 = vr0 + 32 * VT_STR;
            __builtin_amdgcn_s_setprio(1);
#pragma unroll
            for (int js = 0; js < 4; js++) {
                const int co = js * 16 + lh * 8;
                short8 pa0 = *(const short8*)(pr0 + co);
                short8 pa1 = *(const short8*)(pr1 + co);
                short8 vb0 = *(const short8*)(vr0 + co);
                short8 vb1 = *(const short8*)(vr1 + co);
                o00 = mfma_bf16(pa0, vb0, o00);
                o01 = mfma_bf16(pa0, vb1, o01);
                o10 = mfma_bf16(pa1, vb0, o10);
                o11 = mfma_bf16(pa1, vb1, o11);
            }
            __builtin_amdgcn_s_setprio(0);
        }
    }

    // ---------------- epilogue: O / l ----------------
    if (lh == 0 && wjj == 0) l_s[i_my] = l_st;
    __syncthreads();
    float iv[2][16];
#pragma unroll
    for (int it = 0; it < 2; it++)
#pragma unroll
        for (int q = 0; q < 4; q++) {
            float4 l4 = *(float4*)&l_s[it * 32 + 8 * q + 4 * lh];
            iv[it][4*q+0] = 1.f / l4.x; iv[it][4*q+1] = 1.f / l4.y;
            iv[it][4*q+2] = 1.f / l4.z; iv[it][4*q+3] = 1.f / l4.w;
        }
#pragma unroll
    for (int it = 0; it < 2; it++) {
        const floatx16& oa = (it == 0) ? o00 : o10;
        const floatx16& ob = (it == 0) ? o01 : o11;
#pragma unroll
        for (int r = 0; r < 16; r++) {
            const int i = it * 32 + (r & 3) + 8 * (r >> 2) + 4 * lh;
            const size_t rowb = ((size_t)b * NSEQ + q0 + i) * D_DIM;
            out[rowb + w * 64 + l31]      = oa[r] * iv[it][r];
            out[rowb + w * 64 + 32 + l31] = ob[r] * iv[it][r];
        }
    }
#undef ISSUE_QK
#undef ISSUE_V
#undef WRITE_QK
#undef WRITE_V
}

extern "C" void kernel_launch(void* const* d_in, const int* in_sizes, int n_in,
                              void* d_out, int out_size, void* d_ws, size_t ws_size,
                              hipStream_t stream)
{
    (void)in_sizes; (void)n_in; (void)out_size; (void)ws_size;
    const float* x    = (const float*)d_in[0];
    const float* W    = (const float*)d_in[1];
    const float* bias = (const float*)d_in[2];
    float* out = (float*)d_out;

    unsigned short* qs = (unsigned short*)d_ws;              // [16384][512]
    unsigned short* kk = qs + (size_t)16384 * 512;           // [16384][512]
    unsigned short* vT = kk + (size_t)16384 * 512;           // [4][512][4096]
    unsigned short* xb = vT + (size_t)BATCH * D_DIM * NSEQ;  // [16384][512] bf16 x
    unsigned short* Wb = xb + (size_t)16384 * 512;           // [1536][512]  bf16 W

    cast_inputs<<<dim3(4480), 256, 0, stream>>>(x, W, xb, Wb);
    qkv_gemm<<<dim3(12, 128), 256, 0, stream>>>(xb, Wb, bias, qs, kk, vT);
    flash_attn<<<dim3(NSEQ / FA_BQ, BATCH), 512, 0, stream>>>(qs, kk, vT, out);
}

// Round 5
// 375.821 us; speedup vs baseline: 1.9897x; 1.9897x over previous
//
#include <hip/hip_runtime.h>
#include <hip/hip_bf16.h>

#define D_DIM 512
#define NSEQ  4096
#define BATCH 4
#define SCALE 0.125f

typedef __attribute__((ext_vector_type(8)))  short short8;
typedef __attribute__((ext_vector_type(16))) float floatx16;

__device__ __forceinline__ unsigned short f2bf(float f) {
    __hip_bfloat16 h = __float2bfloat16(f);
    return *reinterpret_cast<unsigned short*>(&h);
}

__device__ __forceinline__ floatx16 mfma_bf16(short8 a, short8 b, floatx16 c) {
    return __builtin_amdgcn_mfma_f32_32x32x16_bf16(a, b, c, 0, 0, 0);
}

// global -> LDS direct DMA, 16 B per lane. LDS dest must be wave-uniform base
// (HW adds lane*16). Global source is per-lane.
#define GLOAD16(g, l) __builtin_amdgcn_global_load_lds( \
    (const __attribute__((address_space(1))) unsigned int*)(g), \
    (__attribute__((address_space(3))) unsigned int*)(l), 16, 0, 0)

// ============================================================
// Kernel 0: cast x (4x4096x512) and W (1536x512) fp32 -> bf16.
// ============================================================
__global__ __launch_bounds__(256) void cast_inputs(
    const float* __restrict__ x, const float* __restrict__ W,
    unsigned short* __restrict__ xb, unsigned short* __restrict__ Wb)
{
    const size_t NX = (size_t)BATCH * NSEQ * D_DIM;      // 8388608
    size_t i = ((size_t)blockIdx.x * 256 + threadIdx.x) * 8;
    const float* src; unsigned short* dst;
    if (i < NX) { src = x + i; dst = xb + i; }
    else        { src = W + (i - NX); dst = Wb + (i - NX); }
    float4 v0 = *(const float4*)(src);
    float4 v1 = *(const float4*)(src + 4);
    short8 h;
    h[0] = (short)f2bf(v0.x); h[1] = (short)f2bf(v0.y);
    h[2] = (short)f2bf(v0.z); h[3] = (short)f2bf(v0.w);
    h[4] = (short)f2bf(v1.x); h[5] = (short)f2bf(v1.y);
    h[6] = (short)f2bf(v1.z); h[7] = (short)f2bf(v1.w);
    *(short8*)dst = h;
}

// ============================================================
// Kernel 1: QKV projection. BM=BN=128, BK=64, global_load_lds staging.
// (unchanged from R4 — proven good, ~74 us side)
// ============================================================
__global__ __launch_bounds__(256, 2) void qkv_gemm(
    const unsigned short* __restrict__ xb, const unsigned short* __restrict__ Wb,
    const float* __restrict__ bias,
    unsigned short* __restrict__ qs, unsigned short* __restrict__ kk,
    unsigned short* __restrict__ vT)
{
    __shared__ __align__(16) unsigned short S2[2][128 * 64];
    unsigned short* Xs = S2[0];
    unsigned short* Ws = S2[1];
    unsigned short* Tr = &S2[0][0];                    // [128 d][16 slots x 16B] for V

    const int t = threadIdx.x;
    const int lane = t & 63, w = t >> 6;
    const int l31 = lane & 31, lh = lane >> 5;
    const int wm = w >> 1, we = w & 1;
    const int n0 = blockIdx.x * 128;                   // e-dim (12 blocks)
    const int m0 = blockIdx.y * 128;                   // token-dim (128 blocks)

    floatx16 a00, a01, a10, a11;
#pragma unroll
    for (int r = 0; r < 16; r++) { a00[r] = 0.f; a01[r] = 0.f; a10[r] = 0.f; a11[r] = 0.f; }

    int rowp[4], colp[4];
#pragma unroll
    for (int p = 0; p < 4; p++) {
        int o = p * 4096 + t * 16;
        int row = o >> 7;
        int sl  = ((o >> 4) & 7) ^ (row & 7);
        rowp[p] = row; colp[p] = sl * 8;
    }

    for (int kc = 0; kc < 8; kc++) {
        const int k0 = kc * 64;
        __syncthreads();
#pragma unroll
        for (int p = 0; p < 4; p++) {
            GLOAD16(xb + (size_t)(m0 + rowp[p]) * D_DIM + k0 + colp[p],
                    (char*)Xs + p * 4096 + (t & ~63) * 16);
            GLOAD16(Wb + (size_t)(n0 + rowp[p]) * D_DIM + k0 + colp[p],
                    (char*)Ws + p * 4096 + (t & ~63) * 16);
        }
        __syncthreads();
        const int sw = l31 & 7;
#pragma unroll
        for (int ks = 0; ks < 4; ks++) {
            const int s = ks * 2 + lh;
            const int cof = ((s ^ sw) * 8);
            short8 fa0 = *(const short8*)&Xs[(wm * 64 +      l31) * 64 + cof];
            short8 fa1 = *(const short8*)&Xs[(wm * 64 + 32 + l31) * 64 + cof];
            short8 fb0 = *(const short8*)&Ws[(we * 64 +      l31) * 64 + cof];
            short8 fb1 = *(const short8*)&Ws[(we * 64 + 32 + l31) * 64 + cof];
            a00 = mfma_bf16(fa0, fb0, a00);
            a01 = mfma_bf16(fa0, fb1, a01);
            a10 = mfma_bf16(fa1, fb0, a10);
            a11 = mfma_bf16(fa1, fb1, a11);
        }
    }

    if (n0 < 1024) {
#pragma unroll
        for (int jt = 0; jt < 2; jt++) {
            const int e = n0 + we * 64 + jt * 32 + l31;
            const float bv = bias[e];
#pragma unroll
            for (int it = 0; it < 2; it++) {
                const int mb = m0 + wm * 64 + it * 32;
                const floatx16& av = (it == 0) ? ((jt == 0) ? a00 : a01)
                                               : ((jt == 0) ? a10 : a11);
                if (e < 512) {
#pragma unroll
                    for (int r = 0; r < 16; r++) {
                        int m = mb + (r & 3) + 8 * (r >> 2) + 4 * lh;
                        qs[(size_t)m * D_DIM + e] = f2bf((av[r] + bv) * SCALE);
                    }
                } else {
#pragma unroll
                    for (int r = 0; r < 16; r++) {
                        int m = mb + (r & 3) + 8 * (r >> 2) + 4 * lh;
                        kk[(size_t)m * D_DIM + (e - 512)] = f2bf(av[r] + bv);
                    }
                }
            }
        }
    } else {
        __syncthreads();
#pragma unroll
        for (int jt = 0; jt < 2; jt++) {
            const int dd = we * 64 + jt * 32 + l31;
            const float bv = bias[n0 + dd];
#pragma unroll
            for (int it = 0; it < 2; it++) {
                const floatx16& av = (it == 0) ? ((jt == 0) ? a00 : a01)
                                               : ((jt == 0) ? a10 : a11);
#pragma unroll
                for (int q = 0; q < 4; q++) {
                    int tt = wm * 64 + it * 32 + 8 * q + 4 * lh;
                    ushort4 hv;
                    hv.x = f2bf(av[4 * q + 0] + bv); hv.y = f2bf(av[4 * q + 1] + bv);
                    hv.z = f2bf(av[4 * q + 2] + bv); hv.w = f2bf(av[4 * q + 3] + bv);
                    int byte = dd * 256 + ((((tt >> 3) ^ (dd & 7)) << 4)) + ((tt & 7) << 1);
                    *(ushort4*)((char*)Tr + byte) = hv;
                }
            }
        }
        __syncthreads();
        const int rown = t >> 4;
        const int c    = t & 15;
        const int bb = m0 >> 12, tok0 = (m0 & 4095);
#pragma unroll
        for (int g = 0; g < 8; g++) {
            int row = g * 16 + rown;
            int byte = row * 256 + ((c ^ (row & 7)) << 4);
            uint4 v = *(const uint4*)((char*)Tr + byte);
            *(uint4*)(vT + ((size_t)bb * 512 + (n0 - 1024) + row) * 4096
                      + tok0 + c * 8) = v;
        }
    }
}

// ============================================================
// Kernel 2: flash attention. R1 phase structure (proven 233.5us, no spill),
// but staging via global_load_lds DMA (m151: gload_lds > reg-staging in this
// exact serial 2-barrier shape). Unpadded LDS tiles, XOR-swizzled global
// source + XOR-swizzled ds_read (rule #21). Zero staging registers.
// LDS map (118272 B total):
//   Qc [0,16384)      64 rows x 256B   (swizzled, restaged per dc)
//   Kc [16384,81920)  256 rows x 256B  (swizzled)
//   Vt [0,65536)      512 rows x 128B  (swizzled, union w/ Qc+Kc[0:192))
//   P  [81920,115712) [64][264] shorts (padded, reg-written — unchanged)
//   stats 115712..118272
// ============================================================
#define FA_BQ 64
#define FA_BK 256
#define FA_DC 128
#define P_STR  264

__global__ __launch_bounds__(512, 2) void flash_attn(
    const unsigned short* __restrict__ qs, const unsigned short* __restrict__ kk,
    const unsigned short* __restrict__ vT, float* __restrict__ out)
{
    __shared__ __align__(16) unsigned char smem[118272];
    unsigned short* P  = (unsigned short*)(smem + 81920);    // [64][264]
    float* pmax    = (float*)(smem + 115712);                // [64][4]
    float* psum    = (float*)(smem + 116736);                // [64][4]
    float* alpha_s = (float*)(smem + 117760);                // [64]
    float* l_s     = (float*)(smem + 118016);                // [64]

    const int t = threadIdx.x;
    const int lane = t & 63, w = t >> 6;
    const int l31 = lane & 31, lh = lane >> 5;
    const int wi = w & 1, wjj = w >> 1;
    const int b  = blockIdx.y;
    const int q0 = blockIdx.x * FA_BQ;
    const size_t qbase = ((size_t)b * NSEQ + q0) * D_DIM;
    const size_t kbase = (size_t)b * NSEQ * D_DIM;
    const size_t vbase = (size_t)b * D_DIM * NSEQ;           // vT[b][d][tok]

    const int i_my = wi * 32 + l31;                          // softmax row (0..63)
    const int r7   = l31 & 7;                                // read-swizzle key

    // DMA staging coords. QK tiles: 256B rows, 16 slots; V tile: 128B rows, 8 slots.
    const int qk_r = t >> 4, qk_c = t & 15;                  // +p*32 rows
    const int v_r  = t >> 3, v_c  = t & 7;                   // +p*64 rows
    char* const wbase = (char*)smem + (t & ~63) * 16;        // wave-uniform dest base

    // Q[row][slot s] holds global chunk (s&8)|((s^row)&7); same XOR on read.
#define STAGE_QK(kt_, dc_) do {                                               \
    _Pragma("unroll")                                                         \
    for (int p = 0; p < 2; p++) {                                             \
        int row = p * 32 + qk_r; int sg = (qk_c & 8) | ((qk_c ^ row) & 7);    \
        GLOAD16(qs + qbase + (size_t)row * D_DIM + (dc_) + sg * 8,            \
                wbase + p * 8192);                                            \
    }                                                                         \
    _Pragma("unroll")                                                         \
    for (int p = 0; p < 8; p++) {                                             \
        int row = p * 32 + qk_r; int sg = (qk_c & 8) | ((qk_c ^ row) & 7);    \
        GLOAD16(kk + kbase + (size_t)((kt_) + row) * D_DIM + (dc_) + sg * 8,  \
                wbase + 16384 + p * 8192);                                    \
    }                                                                         \
} while (0)

#define STAGE_V(kt_, jc_) do {                                                \
    _Pragma("unroll")                                                         \
    for (int p = 0; p < 8; p++) {                                             \
        int d = p * 64 + v_r; int sg = (v_c ^ d) & 7;                         \
        GLOAD16(vT + vbase + (size_t)d * NSEQ + (kt_) + (jc_) * 64 + sg * 8,  \
                wbase + p * 8192);                                            \
    }                                                                         \
} while (0)

    floatx16 o00, o01, o10, o11;                             // o[it][dtt]
#pragma unroll
    for (int r = 0; r < 16; r++) { o00[r] = 0.f; o01[r] = 0.f; o10[r] = 0.f; o11[r] = 0.f; }
    float m_st = -__builtin_inff(), l_st = 0.f;

    for (int kt = 0; kt < NSEQ; kt += FA_BK) {
        // ---------------- S^T = K Q^T ----------------
        floatx16 s0, s1;
#pragma unroll
        for (int r = 0; r < 16; r++) { s0[r] = 0.f; s1[r] = 0.f; }

#pragma unroll
        for (int dc = 0; dc < D_DIM; dc += FA_DC) {
            __syncthreads();                                 // prev readers done
            STAGE_QK(kt, dc);
            __syncthreads();                                 // vmcnt(0) drain -> ready
            const char* qrow = (const char*)smem + i_my * 256;
            const char* krow = (const char*)smem + 16384 + (wjj * 64 + l31) * 256;
            __builtin_amdgcn_s_setprio(1);
#pragma unroll
            for (int ks = 0; ks < 8; ks++) {
                const int c = ks * 2 + lh;
                const int off = ((c & 8) | ((c ^ r7) & 7)) * 16;
                short8 fa0 = *(const short8*)(krow + off);
                short8 fa1 = *(const short8*)(krow + 32 * 256 + off);
                short8 fb  = *(const short8*)(qrow + off);
                s0 = mfma_bf16(fa0, fb, s0);
                s1 = mfma_bf16(fa1, fb, s1);
            }
            __builtin_amdgcn_s_setprio(0);
        }

        // ---------------- online softmax (S^T: col=i on lane&31, rows=j) ----
        float mx = -__builtin_inff();
#pragma unroll
        for (int r = 0; r < 16; r++) mx = fmaxf(mx, fmaxf(s0[r], s1[r]));
        mx = fmaxf(mx, __shfl_xor(mx, 32));
        if (lh == 0) pmax[i_my * 4 + wjj] = mx;
        __syncthreads();                                     // B1: Kc/Qc readers done
        STAGE_V(kt, 0);                                      // latency hides under exp/P
        float4 pm = *(float4*)&pmax[i_my * 4];
        const float m_new = fmaxf(m_st, fmaxf(fmaxf(pm.x, pm.y), fmaxf(pm.z, pm.w)));
        const float alpha = __expf(m_st - m_new);
        m_st = m_new;

        float sum = 0.f;
        {
            const int prow = i_my * P_STR;
#pragma unroll
            for (int q = 0; q < 4; q++) {
                float p0 = __expf(s0[4*q+0] - m_new), p1 = __expf(s0[4*q+1] - m_new);
                float p2 = __expf(s0[4*q+2] - m_new), p3 = __expf(s0[4*q+3] - m_new);
                sum += (p0 + p1) + (p2 + p3);
                ushort4 h; h.x = f2bf(p0); h.y = f2bf(p1); h.z = f2bf(p2); h.w = f2bf(p3);
                *(ushort4*)&P[prow + (wjj*2+0)*32 + 8*q + 4*lh] = h;
            }
#pragma unroll
            for (int q = 0; q < 4; q++) {
                float p0 = __expf(s1[4*q+0] - m_new), p1 = __expf(s1[4*q+1] - m_new);
                float p2 = __expf(s1[4*q+2] - m_new), p3 = __expf(s1[4*q+3] - m_new);
                sum += (p0 + p1) + (p2 + p3);
                ushort4 h; h.x = f2bf(p0); h.y = f2bf(p1); h.z = f2bf(p2); h.w = f2bf(p3);
                *(ushort4*)&P[prow + (wjj*2+1)*32 + 8*q + 4*lh] = h;
            }
        }
        sum += __shfl_xor(sum, 32);
        if (lh == 0) psum[i_my * 4 + wjj] = sum;
        if (lh == 0 && wjj == 0) alpha_s[i_my] = alpha;
        __syncthreads();                                     // B2: drains V DMA + P writes
        float4 ps = *(float4*)&psum[i_my * 4];
        l_st = l_st * alpha + ((ps.x + ps.y) + (ps.z + ps.w));

        // ---------------- rescale O by alpha (skip if all == 1) -------------
        float av[2][16];
        bool ch = false;
#pragma unroll
        for (int it = 0; it < 2; it++)
#pragma unroll
            for (int q = 0; q < 4; q++) {
                float4 a4 = *(float4*)&alpha_s[it * 32 + 8 * q + 4 * lh];
                av[it][4*q+0] = a4.x; av[it][4*q+1] = a4.y;
                av[it][4*q+2] = a4.z; av[it][4*q+3] = a4.w;
                ch = ch || (a4.x != 1.f) || (a4.y != 1.f) || (a4.z != 1.f) || (a4.w != 1.f);
            }
        if (__any(ch)) {
#pragma unroll
            for (int r = 0; r < 16; r++) {
                o00[r] *= av[0][r]; o01[r] *= av[0][r];
                o10[r] *= av[1][r]; o11[r] *= av[1][r];
            }
        }

        // ---------------- O += P V  (wave w owns d-chunk w*64) --------------
#pragma unroll
        for (int jc = 0; jc < 4; jc++) {
            if (jc > 0) {
                __syncthreads();                             // prev Vt readers done
                STAGE_V(kt, jc);
                __syncthreads();                             // vmcnt(0) drain -> ready
            }
            const unsigned short* pr0 = &P[l31 * P_STR + jc * 64];
            const unsigned short* pr1 = &P[(32 + l31) * P_STR + jc * 64];
            const char* vrow = (const char*)smem + (w * 64 + l31) * 128;
            __builtin_amdgcn_s_setprio(1);
#pragma unroll
            for (int js = 0; js < 4; js++) {
                const int c = js * 2 + lh;
                const int voff = ((c ^ r7) & 7) * 16;
                const int co = js * 16 + lh * 8;
                short8 pa0 = *(const short8*)(pr0 + co);
                short8 pa1 = *(const short8*)(pr1 + co);
                short8 vb0 = *(const short8*)(vrow + voff);
                short8 vb1 = *(const short8*)(vrow + 32 * 128 + voff);
                o00 = mfma_bf16(pa0, vb0, o00);
                o01 = mfma_bf16(pa0, vb1, o01);
                o10 = mfma_bf16(pa1, vb0, o10);
                o11 = mfma_bf16(pa1, vb1, o11);
            }
            __builtin_amdgcn_s_setprio(0);
        }
    }

    // ---------------- epilogue: O / l ----------------
    if (lh == 0 && wjj == 0) l_s[i_my] = l_st;
    __syncthreads();
    float iv[2][16];
#pragma unroll
    for (int it = 0; it < 2; it++)
#pragma unroll
        for (int q = 0; q < 4; q++) {
            float4 l4 = *(float4*)&l_s[it * 32 + 8 * q + 4 * lh];
            iv[it][4*q+0] = 1.f / l4.x; iv[it][4*q+1] = 1.f / l4.y;
            iv[it][4*q+2] = 1.f / l4.z; iv[it][4*q+3] = 1.f / l4.w;
        }
#pragma unroll
    for (int it = 0; it < 2; it++) {
        const floatx16& oa = (it == 0) ? o00 : o10;
        const floatx16& ob = (it == 0) ? o01 : o11;
#pragma unroll
        for (int r = 0; r < 16; r++) {
            const int i = it * 32 + (r & 3) + 8 * (r >> 2) + 4 * lh;
            const size_t rowb = ((size_t)b * NSEQ + q0 + i) * D_DIM;
            out[rowb + w * 64 + l31]      = oa[r] * iv[it][r];
            out[rowb + w * 64 + 32 + l31] = ob[r] * iv[it][r];
        }
    }
#undef STAGE_QK
#undef STAGE_V
}

extern "C" void kernel_launch(void* const* d_in, const int* in_sizes, int n_in,
                              void* d_out, int out_size, void* d_ws, size_t ws_size,
                              hipStream_t stream)
{
    (void)in_sizes; (void)n_in; (void)out_size; (void)ws_size;
    const float* x    = (const float*)d_in[0];
    const float* W    = (const float*)d_in[1];
    const float* bias = (const float*)d_in[2];
    float* out = (float*)d_out;

    unsigned short* qs = (unsigned short*)d_ws;              // [16384][512]
    unsigned short* kk = qs + (size_t)16384 * 512;           // [16384][512]
    unsigned short* vT = kk + (size_t)16384 * 512;           // [4][512][4096]
    unsigned short* xb = vT + (size_t)BATCH * D_DIM * NSEQ;  // [16384][512] bf16 x
    unsigned short* Wb = xb + (size_t)16384 * 512;           // [1536][512]  bf16 W

    cast_inputs<<<dim3(4480), 256, 0, stream>>>(x, W, xb, Wb);
    qkv_gemm<<<dim3(12, 128), 256, 0, stream>>>(xb, Wb, bias, qs, kk, vT);
    flash_attn<<<dim3(NSEQ / FA_BQ, BATCH), 512, 0, stream>>>(qs, kk, vT, out);
}